// Round 7
// baseline (513.627 us; speedup 1.0000x reference)
//
#include <hip/hip_runtime.h>

// Problem constants: B=2, S=2048, D=1024, H=16, Hd=64
#define S_   2048
#define D_   1024

typedef __attribute__((ext_vector_type(8))) __bf16 bf16x8;
typedef __attribute__((ext_vector_type(4))) __bf16 bf16x4;
typedef __attribute__((ext_vector_type(4))) float f32x4;
typedef __attribute__((ext_vector_type(4))) float float4v;
typedef __attribute__((ext_vector_type(2))) unsigned int u32x2;
typedef __attribute__((ext_vector_type(4))) unsigned int u32x4;

// Workspace layout (in bf16/short elements)
#define XQ_OFF   0           // 4096x1024 bf16 inputs
#define XK_OFF   4194304
#define XV_OFF   8388608
#define WQT_OFF  12582912    // W^T 1024x1024 bf16, [n][k]
#define WKT_OFF  13631488
#define WVT_OFF  14680064
#define WOT_OFF  15728640
#define QH_OFF   16777216    // (B,H,S,Hd) bf16, PRE-SCALED by log2e/8
#define KH_OFF   20971520    // (B,H,S,Hd) bf16
#define VHT_OFF  25165824    // (B,H)(S/128 kt)(64 hd)(128 s) bf16 blocked V^T
#define CTX_OFF  29360128    // (B,S,D) bf16
#define WS_BYTES 67108864ULL

// exp base-2: scores are pre-scaled by log2(e)/temperature, so softmax is
// exp2-exact.
#if __has_builtin(__builtin_amdgcn_exp2f)
#define EXP2(x) __builtin_amdgcn_exp2f(x)
#else
#define EXP2(x) __expf((x) * 0.69314718056f)
#endif
#define QSCALE 0.1803368801f  // 0.125 * log2(e)

__device__ __forceinline__ unsigned short f2b(float f) {  // fp32->bf16 RNE
  unsigned u = __builtin_bit_cast(unsigned, f);
  u += 0x7fffu + ((u >> 16) & 1u);
  return (unsigned short)(u >> 16);
}

// ---------------- K0a: fp32 -> bf16 convert for q,k,v ----------------
__global__ __launch_bounds__(256) void cvt_qkv(const float* __restrict__ q,
    const float* __restrict__ k, const float* __restrict__ v,
    short* __restrict__ ws) {
  const float* src = (blockIdx.y == 0) ? q : (blockIdx.y == 1) ? k : v;
  short* dst = ws + (size_t)blockIdx.y * 4194304;
  size_t t = (size_t)blockIdx.x * 256 + threadIdx.x;   // 1,048,576 threads
  float4v f = *(const float4v*)(src + t * 4);
  u32x2 p;
  p[0] = (unsigned)f2b(f[0]) | ((unsigned)f2b(f[1]) << 16);
  p[1] = (unsigned)f2b(f[2]) | ((unsigned)f2b(f[3]) << 16);
  *(u32x2*)(dst + t * 4) = p;
}

// ------------- K0b: weights fp32 (K x N) -> bf16 W^T (N x K) -------------
__global__ __launch_bounds__(256) void cvt_wt(const float* __restrict__ wq,
    const float* __restrict__ wk, const float* __restrict__ wv,
    const float* __restrict__ wo, short* __restrict__ ws) {
  __shared__ float tile[32][33];
  int z = blockIdx.z;
  const float* W = (z == 0) ? wq : (z == 1) ? wk : (z == 2) ? wv : wo;
  short* Wt = ws + WQT_OFF + (size_t)z * 1048576;
  int tx = threadIdx.x, ty = threadIdx.y;  // 32 x 8
#pragma unroll
  for (int i = 0; i < 4; ++i)
    tile[ty + i * 8][tx] =
        W[(size_t)(blockIdx.y * 32 + ty + i * 8) * D_ + blockIdx.x * 32 + tx];
  __syncthreads();
#pragma unroll
  for (int i = 0; i < 4; ++i)
    Wt[(size_t)(blockIdx.x * 32 + ty + i * 8) * D_ + blockIdx.y * 32 + tx] =
        (short)f2b(tile[tx][ty + i * 8]);
}

// ---------------- K1/K3: bf16 GEMM, 128x128 tile, 2-phase ----------------
// C(4096x1024) = A(4096x1024) * B(1024x1024) + bias ; B given as B^T [n][k]
__device__ __forceinline__ void stage_tile(const short* __restrict__ g,
                                           short* l, int w, int lane) {
  // tile [128 rows][64 k] bf16, linear LDS; 16B per lane per call
  int lrow = lane >> 3, lcol = (lane & 7) * 8;
#pragma unroll
  for (int c = 0; c < 4; ++c) {
    int seg = c * 4 + w;  // 0..15, 8 rows each
    const short* gp = g + (size_t)(seg * 8 + lrow) * 1024 + lcol;
    short* lp = l + seg * 512 + lane * 8;
    __builtin_amdgcn_global_load_lds(
        (const __attribute__((address_space(1))) void*)gp,
        (__attribute__((address_space(3))) void*)lp, 16, 0, 0);
  }
}

__global__ __launch_bounds__(256) void gemm_bf16(short* __restrict__ ws,
    const float* __restrict__ bq, const float* __restrict__ bk,
    const float* __restrict__ bv, const float* __restrict__ bo,
    float* __restrict__ out, int mode_base) {
  const int tid = threadIdx.x, lane = tid & 63, w = tid >> 6;
  const int wm = w >> 1, wn = w & 1;
  const int ln15 = lane & 15, g = lane >> 4;
  const int bm = blockIdx.y, bn = blockIdx.x;
  const int mode = (mode_base == 3) ? 3 : (int)blockIdx.z;

  const short* A; const short* Bt; const float* bias;
  if (mode == 0)      { A = ws + XQ_OFF;  Bt = ws + WQT_OFF; bias = bq; }
  else if (mode == 1) { A = ws + XK_OFF;  Bt = ws + WKT_OFF; bias = bk; }
  else if (mode == 2) { A = ws + XV_OFF;  Bt = ws + WVT_OFF; bias = bv; }
  else                { A = ws + CTX_OFF; Bt = ws + WOT_OFF; bias = bo; }

  __shared__ short smem[2][2][8192];   // [A/B][dbuf][128*64]
  short (*sA)[8192] = smem[0];
  short (*sB)[8192] = smem[1];

  f32x4 acc[4][4] = {};

  const short* Ab = A + (size_t)bm * 128 * 1024;
  const short* Bb = Bt + (size_t)bn * 128 * 1024;

  stage_tile(Ab, sA[0], w, lane);
  stage_tile(Bb, sB[0], w, lane);
  __syncthreads();

  int cur = 0;
#pragma unroll 1
  for (int kt = 0; kt < 16; ++kt) {
    if (kt < 15) {
      stage_tile(Ab + (kt + 1) * 64, sA[cur ^ 1], w, lane);
      stage_tile(Bb + (kt + 1) * 64, sB[cur ^ 1], w, lane);
    }
#pragma unroll
    for (int kk = 0; kk < 2; ++kk) {
      bf16x8 af[4], bfr[4];
#pragma unroll
      for (int m = 0; m < 4; ++m)
        af[m] = *(const bf16x8*)&sA[cur][(wm * 64 + m * 16 + ln15) * 64 + kk * 32 + g * 8];
#pragma unroll
      for (int n = 0; n < 4; ++n)
        bfr[n] = *(const bf16x8*)&sB[cur][(wn * 64 + n * 16 + ln15) * 64 + kk * 32 + g * 8];
#pragma unroll
      for (int m = 0; m < 4; ++m)
#pragma unroll
        for (int n = 0; n < 4; ++n)
          acc[m][n] = __builtin_amdgcn_mfma_f32_16x16x32_bf16(af[m], bfr[n], acc[m][n], 0, 0, 0);
    }
    __syncthreads();
    cur ^= 1;
  }

  float bb[4];
#pragma unroll
  for (int n = 0; n < 4; ++n) bb[n] = bias[bn * 128 + wn * 64 + n * 16 + ln15];

  if (mode == 3) {
#pragma unroll
    for (int m = 0; m < 4; ++m) {
      int row0 = bm * 128 + wm * 64 + m * 16 + g * 4;
#pragma unroll
      for (int n = 0; n < 4; ++n) {
        int col = bn * 128 + wn * 64 + n * 16 + ln15;
#pragma unroll
        for (int r = 0; r < 4; ++r)
          out[(size_t)(row0 + r) * 1024 + col] = acc[m][n][r] + bb[n];
      }
    }
    return;
  }

  // ---- modes 0/1/2: stage C tile (bf16, bias+scale applied) to LDS,
  //      then fully-coalesced 16B writes ----
  float sc = (mode == 0) ? QSCALE : 1.0f;
  short (*tile)[136] = (short(*)[136])smem;  // 128x136 bf16 = 34.8KB < 64KB
#pragma unroll
  for (int m = 0; m < 4; ++m)
#pragma unroll
    for (int n = 0; n < 4; ++n)
#pragma unroll
      for (int r = 0; r < 4; ++r)
        tile[wm * 64 + m * 16 + g * 4 + r][wn * 64 + n * 16 + ln15] =
            (short)f2b((acc[m][n][r] + bb[n]) * sc);
  __syncthreads();

  if (mode == 2) {
    // blocked vht: [bh][sblk(16)][hd(64)][s(128)], each kt-tile 16KB contig
    int dcol = tid >> 1, sh = (tid & 1) * 64;
    int colg = bn * 128 + dcol, h = colg >> 6, hd = colg & 63;
    int b = bm >> 4, sblk = bm & 15;
    short* dst = ws + VHT_OFF +
                 ((size_t)((b * 16 + h) * 16 + sblk)) * 8192 + hd * 128 + sh;
#pragma unroll
    for (int j = 0; j < 8; ++j) {
      u32x4 pk;
#pragma unroll
      for (int q = 0; q < 4; ++q) {
        unsigned lo = (unsigned short)tile[sh + j * 8 + q * 2][dcol];
        unsigned hi = (unsigned short)tile[sh + j * 8 + q * 2 + 1][dcol];
        pk[q] = lo | (hi << 16);
      }
      *(u32x4*)(dst + j * 8) = pk;
    }
  } else {
    // qh/kh (B,H,S,Hd): row = s, 64 hd contiguous per (h,s)
    int r = tid >> 1, sh = (tid & 1) * 64;
    int colg = bn * 128 + sh, h = colg >> 6;
    int sg = bm * 128 + r, b = sg >> 11, sl = sg & 2047;
    short* dst = ws + ((mode == 0) ? QH_OFF : KH_OFF) +
                 (((size_t)(b * 16 + h)) * 2048 + sl) * 64;
#pragma unroll
    for (int j = 0; j < 8; ++j)
      *(u32x4*)(dst + j * 8) = *(const u32x4*)&tile[r][sh + j * 8];
  }
}

// ---------------- K2: fused attention, 4 waves x 16 q-rows, NO barriers ----
// Swapped QK^T: D = mfma(K, Q) = S^T. Per 2-kt group, P (bf16) accumulates in
// Pl[64][256+pad] (rows wave-private), then each attn row is stored as ONE
// wave-contiguous 1KB f32 instruction. PLAIN cached stores (r7): nontemporal
// was the r2-r6 store-BW cap (~1.5-2 TB/s vs fill kernel's 6.7 TB/s through
// L2 write-back). L2 pollution is moot: K/V working set is 12 MB.
__global__ __launch_bounds__(256) void attn_k(short* __restrict__ ws,
                                              float* __restrict__ attn) {
  const int tid = threadIdx.x, lane = tid & 63, w = tid >> 6;  // 4 waves
  const int ln15 = lane & 15, g = lane >> 4;
  // XCD-affine swizzle: same-bh blocks land on the same XCD (K/V L2 reuse)
  int bid = blockIdx.x;                 // 1024 blocks
  int qt = (bid >> 3) & 31;             // 32 q-tiles of 64 rows
  int bh = (bid & 7) + 8 * (bid >> 8);  // 4 bh per XCD
  const int q0 = qt * 64;

  const short* Q  = ws + QH_OFF  + ((size_t)bh * 2048 + q0) * 64;
  const short* K  = ws + KH_OFF  + (size_t)bh * 2048 * 64;
  const short* Vt = ws + VHT_OFF + (size_t)bh * 131072;

  __shared__ short Pl[64][264];  // 33.8 KB; 2-kt P buffer, rows wave-private

  // Q B-frags: wave w owns q rows [w*16, w*16+16)
  bf16x8 qf0 = *(const bf16x8*)&Q[(w * 16 + ln15) * 64 + g * 8];
  bf16x8 qf1 = *(const bf16x8*)&Q[(w * 16 + ln15) * 64 + 32 + g * 8];

  // ---- pass 1: softmax denominators (exp2; scores pre-scaled by log2e) ----
  float ps0 = 0.f, ps1 = 0.f;
#pragma unroll 1
  for (int kt = 0; kt < 16; ++kt) {
    const short* Kt = K + kt * 8192;
#pragma unroll 4
    for (int m = 0; m < 8; ++m) {
      bf16x8 ka0 = *(const bf16x8*)&Kt[(m * 16 + ln15) * 64 + g * 8];
      bf16x8 ka1 = *(const bf16x8*)&Kt[(m * 16 + ln15) * 64 + 32 + g * 8];
      f32x4 c = {0.f, 0.f, 0.f, 0.f};
      c = __builtin_amdgcn_mfma_f32_16x16x32_bf16(ka0, qf0, c, 0, 0, 0);
      c = __builtin_amdgcn_mfma_f32_16x16x32_bf16(ka1, qf1, c, 0, 0, 0);
      ps0 += EXP2(c[0]) + EXP2(c[1]);
      ps1 += EXP2(c[2]) + EXP2(c[3]);
    }
  }
  float ps = ps0 + ps1;
  ps += __shfl_xor(ps, 16, 64);  // reduce the 4 k-groups (same q col)
  ps += __shfl_xor(ps, 32, 64);
  float ri = 1.0f / ps;

  // ---- pass 2: QK^T -> P(2 kt in LDS) -> 1KB attn stores -> PV ----
  f32x4 cacc[4] = {};
#pragma unroll 1
  for (int ktp = 0; ktp < 8; ++ktp) {
#pragma unroll
    for (int half = 0; half < 2; ++half) {
      const short* Kt = K + (ktp * 2 + half) * 8192;
#pragma unroll 4
      for (int m = 0; m < 8; ++m) {
        bf16x8 ka0 = *(const bf16x8*)&Kt[(m * 16 + ln15) * 64 + g * 8];
        bf16x8 ka1 = *(const bf16x8*)&Kt[(m * 16 + ln15) * 64 + 32 + g * 8];
        f32x4 c = {0.f, 0.f, 0.f, 0.f};
        c = __builtin_amdgcn_mfma_f32_16x16x32_bf16(ka0, qf0, c, 0, 0, 0);
        c = __builtin_amdgcn_mfma_f32_16x16x32_bf16(ka1, qf1, c, 0, 0, 0);
        bf16x4 pb;
        pb[0] = (__bf16)(EXP2(c[0]) * ri);
        pb[1] = (__bf16)(EXP2(c[1]) * ri);
        pb[2] = (__bf16)(EXP2(c[2]) * ri);
        pb[3] = (__bf16)(EXP2(c[3]) * ri);
        *(bf16x4*)&Pl[w * 16 + ln15][half * 128 + m * 16 + g * 4] = pb;
      }
    }
    asm volatile("s_waitcnt lgkmcnt(0)" ::: "memory");  // own P writes visible

    // attn store: one 1KB wave-contiguous PLAIN store per q row (via L2);
    // the PV MFMA cluster below hides the issue latency.
    float* ab = attn + ((size_t)(bh * 2048 + q0 + w * 16)) * 2048 +
                ktp * 256 + lane * 4;
#pragma unroll
    for (int r = 0; r < 16; ++r) {
      bf16x4 pv = *(const bf16x4*)&Pl[w * 16 + r][lane * 4];
      float4v o;
      o[0] = (float)pv[0]; o[1] = (float)pv[1];
      o[2] = (float)pv[2]; o[3] = (float)pv[3];
      *(float4v*)(ab + (size_t)r * 2048) = o;
    }

    // PV for both kt halves (V^T kt-tiles contiguous, L1/L2-shared by waves)
#pragma unroll
    for (int half = 0; half < 2; ++half) {
      const short* Vk = Vt + (ktp * 2 + half) * 8192;
#pragma unroll
      for (int kk = 0; kk < 4; ++kk) {
        bf16x8 pa =
            *(const bf16x8*)&Pl[w * 16 + ln15][half * 128 + kk * 32 + g * 8];
#pragma unroll
        for (int n = 0; n < 4; ++n) {
          bf16x8 vb =
              *(const bf16x8*)&Vk[(n * 16 + ln15) * 128 + kk * 32 + g * 8];
          cacc[n] =
              __builtin_amdgcn_mfma_f32_16x16x32_bf16(pa, vb, cacc[n], 0, 0, 0);
        }
      }
    }
  }

  // ctx epilogue -> (B,S,D) bf16, repacked via LDS to 128B row stores
  {
    short* Pw = &Pl[w * 16][0];  // reuse; per-wave region [16 rows][264]
#pragma unroll
    for (int n = 0; n < 4; ++n)
#pragma unroll
      for (int r = 0; r < 4; ++r)
        Pw[(g * 4 + r) * 264 + n * 16 + ln15] = (short)f2b(cacc[n][r]);
    asm volatile("s_waitcnt lgkmcnt(0)" ::: "memory");
    int b = bh >> 4, h = bh & 15;
    int row = lane >> 3, col = (lane & 7) * 8;  // 8 rows x 16B = 128B/row
#pragma unroll
    for (int i = 0; i < 2; ++i) {
      int q = q0 + w * 16 + i * 8 + row;
      u32x4 pk = *(const u32x4*)&Pw[(i * 8 + row) * 264 + col];
      *(u32x4*)&ws[CTX_OFF + ((size_t)(b * 2048 + q)) * 1024 + h * 64 + col] = pk;
    }
  }
}

extern "C" void kernel_launch(void* const* d_in, const int* in_sizes, int n_in,
                              void* d_out, int out_size, void* d_ws, size_t ws_size,
                              hipStream_t stream) {
  const float* q  = (const float*)d_in[0];
  const float* k  = (const float*)d_in[1];
  const float* v  = (const float*)d_in[2];
  const float* wq = (const float*)d_in[3];
  const float* bq = (const float*)d_in[4];
  const float* wk = (const float*)d_in[5];
  const float* bk = (const float*)d_in[6];
  const float* wv = (const float*)d_in[7];
  const float* bv = (const float*)d_in[8];
  const float* wo = (const float*)d_in[9];
  const float* bo = (const float*)d_in[10];
  float* out  = (float*)d_out;
  float* attn = out + 4194304;  // out (2,2048,1024) then attn (2,16,2048,2048)
  short* ws = (short*)d_ws;
  if (ws_size < WS_BYTES) return;  // need 64 MB scratch

  cvt_qkv<<<dim3(4096, 3), 256, 0, stream>>>(q, k, v, ws);
  cvt_wt<<<dim3(32, 32, 4), dim3(32, 8), 0, stream>>>(wq, wk, wv, wo, ws);
  gemm_bf16<<<dim3(8, 32, 3), 256, 0, stream>>>(ws, bq, bk, bv, bo, out, 0);
  attn_k<<<dim3(1024), 256, 0, stream>>>(ws, attn);
  gemm_bf16<<<dim3(8, 32, 1), 256, 0, stream>>>(ws, bq, bk, bv, bo, out, 3);
}

// Round 8
// 269.016 us; speedup vs baseline: 1.9093x; 1.9093x over previous
//
#include <hip/hip_runtime.h>

// Problem constants: B=2, S=2048, D=1024, H=16, Hd=64
#define S_   2048
#define D_   1024

typedef __attribute__((ext_vector_type(8))) __bf16 bf16x8;
typedef __attribute__((ext_vector_type(4))) __bf16 bf16x4;
typedef __attribute__((ext_vector_type(4))) float f32x4;
typedef __attribute__((ext_vector_type(4))) float float4v;
typedef __attribute__((ext_vector_type(2))) unsigned int u32x2;
typedef __attribute__((ext_vector_type(4))) unsigned int u32x4;

// Workspace layout (in bf16/short elements)
#define XQ_OFF   0           // 4096x1024 bf16 inputs
#define XK_OFF   4194304
#define XV_OFF   8388608
#define WQT_OFF  12582912    // W^T 1024x1024 bf16, [n][k]
#define WKT_OFF  13631488
#define WVT_OFF  14680064
#define WOT_OFF  15728640
#define QH_OFF   16777216    // (B,H,S,Hd) bf16, PRE-SCALED by log2e/8
#define KH_OFF   20971520    // (B,H,S,Hd) bf16
#define VHT_OFF  25165824    // (B,H)(sblk 16)(hd 64)(s 128) bf16 blocked V^T
#define CTX_OFF  29360128    // (B,S,D) bf16
#define WS_BYTES 67108864ULL

#if __has_builtin(__builtin_amdgcn_exp2f)
#define EXP2(x) __builtin_amdgcn_exp2f(x)
#else
#define EXP2(x) __expf((x) * 0.69314718056f)
#endif
#define QSCALE 0.1803368801f  // 0.125 * log2(e)

__device__ __forceinline__ unsigned short f2b(float f) {  // fp32->bf16 RNE
  unsigned u = __builtin_bit_cast(unsigned, f);
  u += 0x7fffu + ((u >> 16) & 1u);
  return (unsigned short)(u >> 16);
}
__device__ __forceinline__ float b2f(unsigned s) {
  return __builtin_bit_cast(float, s << 16);
}

// ---------------- K0a: fp32 -> bf16 convert for q,k,v ----------------
__global__ __launch_bounds__(256) void cvt_qkv(const float* __restrict__ q,
    const float* __restrict__ k, const float* __restrict__ v,
    short* __restrict__ ws) {
  const float* src = (blockIdx.y == 0) ? q : (blockIdx.y == 1) ? k : v;
  short* dst = ws + (size_t)blockIdx.y * 4194304;
  size_t t = (size_t)blockIdx.x * 256 + threadIdx.x;   // 1,048,576 threads
  float4v f = *(const float4v*)(src + t * 4);
  u32x2 p;
  p[0] = (unsigned)f2b(f[0]) | ((unsigned)f2b(f[1]) << 16);
  p[1] = (unsigned)f2b(f[2]) | ((unsigned)f2b(f[3]) << 16);
  *(u32x2*)(dst + t * 4) = p;
}

// ------------- K0b: weights fp32 (K x N) -> bf16 W^T (N x K) -------------
__global__ __launch_bounds__(256) void cvt_wt(const float* __restrict__ wq,
    const float* __restrict__ wk, const float* __restrict__ wv,
    const float* __restrict__ wo, short* __restrict__ ws) {
  __shared__ float tile[32][33];
  int z = blockIdx.z;
  const float* W = (z == 0) ? wq : (z == 1) ? wk : (z == 2) ? wv : wo;
  short* Wt = ws + WQT_OFF + (size_t)z * 1048576;
  int tx = threadIdx.x, ty = threadIdx.y;  // 32 x 8
#pragma unroll
  for (int i = 0; i < 4; ++i)
    tile[ty + i * 8][tx] =
        W[(size_t)(blockIdx.y * 32 + ty + i * 8) * D_ + blockIdx.x * 32 + tx];
  __syncthreads();
#pragma unroll
  for (int i = 0; i < 4; ++i)
    Wt[(size_t)(blockIdx.x * 32 + ty + i * 8) * D_ + blockIdx.y * 32 + tx] =
        (short)f2b(tile[tx][ty + i * 8]);
}

// ---------------- K1/K3: bf16 GEMM, 128x128 tile, 2-phase ----------------
__device__ __forceinline__ void stage_tile(const short* __restrict__ g,
                                           short* l, int w, int lane) {
  int lrow = lane >> 3, lcol = (lane & 7) * 8;
#pragma unroll
  for (int c = 0; c < 4; ++c) {
    int seg = c * 4 + w;  // 0..15, 8 rows each
    const short* gp = g + (size_t)(seg * 8 + lrow) * 1024 + lcol;
    short* lp = l + seg * 512 + lane * 8;
    __builtin_amdgcn_global_load_lds(
        (const __attribute__((address_space(1))) void*)gp,
        (__attribute__((address_space(3))) void*)lp, 16, 0, 0);
  }
}

__global__ __launch_bounds__(256) void gemm_bf16(short* __restrict__ ws,
    const float* __restrict__ bq, const float* __restrict__ bk,
    const float* __restrict__ bv, const float* __restrict__ bo,
    float* __restrict__ out, int mode_base) {
  const int tid = threadIdx.x, lane = tid & 63, w = tid >> 6;
  const int wm = w >> 1, wn = w & 1;
  const int ln15 = lane & 15, g = lane >> 4;
  const int bm = blockIdx.y, bn = blockIdx.x;
  const int mode = (mode_base == 3) ? 3 : (int)blockIdx.z;

  const short* A; const short* Bt; const float* bias;
  if (mode == 0)      { A = ws + XQ_OFF;  Bt = ws + WQT_OFF; bias = bq; }
  else if (mode == 1) { A = ws + XK_OFF;  Bt = ws + WKT_OFF; bias = bk; }
  else if (mode == 2) { A = ws + XV_OFF;  Bt = ws + WVT_OFF; bias = bv; }
  else                { A = ws + CTX_OFF; Bt = ws + WOT_OFF; bias = bo; }

  __shared__ short smem[2][2][8192];   // [A/B][dbuf][128*64]
  short (*sA)[8192] = smem[0];
  short (*sB)[8192] = smem[1];

  f32x4 acc[4][4] = {};

  const short* Ab = A + (size_t)bm * 128 * 1024;
  const short* Bb = Bt + (size_t)bn * 128 * 1024;

  stage_tile(Ab, sA[0], w, lane);
  stage_tile(Bb, sB[0], w, lane);
  __syncthreads();

  int cur = 0;
#pragma unroll 1
  for (int kt = 0; kt < 16; ++kt) {
    if (kt < 15) {
      stage_tile(Ab + (kt + 1) * 64, sA[cur ^ 1], w, lane);
      stage_tile(Bb + (kt + 1) * 64, sB[cur ^ 1], w, lane);
    }
#pragma unroll
    for (int kk = 0; kk < 2; ++kk) {
      bf16x8 af[4], bfr[4];
#pragma unroll
      for (int m = 0; m < 4; ++m)
        af[m] = *(const bf16x8*)&sA[cur][(wm * 64 + m * 16 + ln15) * 64 + kk * 32 + g * 8];
#pragma unroll
      for (int n = 0; n < 4; ++n)
        bfr[n] = *(const bf16x8*)&sB[cur][(wn * 64 + n * 16 + ln15) * 64 + kk * 32 + g * 8];
#pragma unroll
      for (int m = 0; m < 4; ++m)
#pragma unroll
        for (int n = 0; n < 4; ++n)
          acc[m][n] = __builtin_amdgcn_mfma_f32_16x16x32_bf16(af[m], bfr[n], acc[m][n], 0, 0, 0);
    }
    __syncthreads();
    cur ^= 1;
  }

  float bb[4];
#pragma unroll
  for (int n = 0; n < 4; ++n) bb[n] = bias[bn * 128 + wn * 64 + n * 16 + ln15];

  if (mode == 3) {
#pragma unroll
    for (int m = 0; m < 4; ++m) {
      int row0 = bm * 128 + wm * 64 + m * 16 + g * 4;
#pragma unroll
      for (int n = 0; n < 4; ++n) {
        int col = bn * 128 + wn * 64 + n * 16 + ln15;
#pragma unroll
        for (int r = 0; r < 4; ++r)
          out[(size_t)(row0 + r) * 1024 + col] = acc[m][n][r] + bb[n];
      }
    }
    return;
  }

  float sc = (mode == 0) ? QSCALE : 1.0f;
  short (*tile)[136] = (short(*)[136])smem;  // 128x136 bf16
#pragma unroll
  for (int m = 0; m < 4; ++m)
#pragma unroll
    for (int n = 0; n < 4; ++n)
#pragma unroll
      for (int r = 0; r < 4; ++r)
        tile[wm * 64 + m * 16 + g * 4 + r][wn * 64 + n * 16 + ln15] =
            (short)f2b((acc[m][n][r] + bb[n]) * sc);
  __syncthreads();

  if (mode == 2) {
    // blocked vht: [bh][sblk(16)][hd(64)][s(128)]
    int dcol = tid >> 1, sh = (tid & 1) * 64;
    int colg = bn * 128 + dcol, h = colg >> 6, hd = colg & 63;
    int b = bm >> 4, sblk = bm & 15;
    short* dst = ws + VHT_OFF +
                 ((size_t)((b * 16 + h) * 16 + sblk)) * 8192 + hd * 128 + sh;
#pragma unroll
    for (int j = 0; j < 8; ++j) {
      u32x4 pk;
#pragma unroll
      for (int q = 0; q < 4; ++q) {
        unsigned lo = (unsigned short)tile[sh + j * 8 + q * 2][dcol];
        unsigned hi = (unsigned short)tile[sh + j * 8 + q * 2 + 1][dcol];
        pk[q] = lo | (hi << 16);
      }
      *(u32x4*)(dst + j * 8) = pk;
    }
  } else {
    int r = tid >> 1, sh = (tid & 1) * 64;
    int colg = bn * 128 + sh, h = colg >> 6;
    int sg = bm * 128 + r, b = sg >> 11, sl = sg & 2047;
    short* dst = ws + ((mode == 0) ? QH_OFF : KH_OFF) +
                 (((size_t)(b * 16 + h)) * 2048 + sl) * 64;
#pragma unroll
    for (int j = 0; j < 8; ++j)
      *(u32x4*)(dst + j * 8) = *(const u32x4*)&tile[r][sh + j * 8];
  }
}

// ---------------- K2: fused attention, GEMM-style LDS staging ----------
// Root cause of r2-r7 (~400us, all pipes idle): per-lane strided vector
// loads -> 16 L1/TA transactions per instruction, x 770 loads x 16 waves/CU
// = address-path serialization. Fix: stage K/V per BLOCK via
// global_load_lds (XOR-swizzled source, linear LDS dest, T2/m173), 8 waves
// share each tile via ds_read_b128. Counted vmcnt(16) before raw s_barrier:
// the 2 staging loads (older) drain, the 16 attn stores (younger) stay in
// flight across the barrier.
__global__ __launch_bounds__(512) void attn_k(short* __restrict__ ws,
                                              float* __restrict__ attn) {
  const int tid = threadIdx.x, lane = tid & 63, w = tid >> 6;  // 8 waves
  const int ln15 = lane & 15, g = lane >> 4;
  // XCD-affine swizzle: same-bh blocks land on the same XCD
  int bid = blockIdx.x;                  // 512 blocks
  int qt = (bid >> 3) & 15;              // 16 q-tiles of 128 rows
  int bh = (bid & 7) + 8 * (bid >> 7);   // 4 bh per XCD
  const int q0 = qt * 128;

  const short* Q  = ws + QH_OFF  + ((size_t)bh * 2048 + q0) * 64;
  const short* K  = ws + KH_OFF  + (size_t)bh * 2048 * 64;
  const short* Vt = ws + VHT_OFF + (size_t)bh * 131072;

  __shared__ short sK[2][4096];   // [64 k][64 d] bf16, XOR-swizzled chunks
  __shared__ short sV[2][4096];   // [64 hd][64 s] bf16, XOR-swizzled chunks
  __shared__ short Pl[128][72];   // P bf16, 144B row stride (16B-aligned)

  // staging decomposition: 512 threads x 16B = one 8KB tile per call.
  // LDS[row][c] = G[row][c ^ (row&7)]  (16B chunks; involution)
  const int srow = tid >> 3, sc = tid & 7;
  const int scsw = sc ^ (srow & 7);
  const int sdst = tid * 8;  // short offset; byte = tid*16

#define STAGE_K(kt, buf)                                                     \
  __builtin_amdgcn_global_load_lds(                                         \
      (const __attribute__((address_space(1))) void*)(K + ((kt) * 64 + srow) * 64 + scsw * 8), \
      (__attribute__((address_space(3))) void*)(&sK[buf][sdst]), 16, 0, 0)
#define STAGE_V(kt, buf)                                                     \
  __builtin_amdgcn_global_load_lds(                                         \
      (const __attribute__((address_space(1))) void*)(Vt + ((kt) >> 1) * 8192 + srow * 128 + ((kt) & 1) * 64 + scsw * 8), \
      (__attribute__((address_space(3))) void*)(&sV[buf][sdst]), 16, 0, 0)

  // Q fragments: wave w owns q rows [w*16, w*16+16)
  bf16x8 qf0 = *(const bf16x8*)&Q[(w * 16 + ln15) * 64 + g * 8];
  bf16x8 qf1 = *(const bf16x8*)&Q[(w * 16 + ln15) * 64 + 32 + g * 8];

  // ---- pass 1: softmax denominators ----
  STAGE_K(0, 0);
  asm volatile("s_waitcnt vmcnt(0)" ::: "memory");
  __builtin_amdgcn_s_barrier();

  float ps0 = 0.f, ps1 = 0.f;
  int cur = 0;
#pragma unroll 1
  for (int kt = 0; kt < 32; ++kt) {
    if (kt < 31) STAGE_K(kt + 1, cur ^ 1);
#pragma unroll
    for (int m = 0; m < 4; ++m) {
      int r = m * 16 + ln15;
      bf16x8 ka0 = *(const bf16x8*)&sK[cur][r * 64 + ((g ^ (r & 7)) * 8)];
      bf16x8 ka1 = *(const bf16x8*)&sK[cur][r * 64 + (((4 + g) ^ (r & 7)) * 8)];
      f32x4 c = {0.f, 0.f, 0.f, 0.f};
      c = __builtin_amdgcn_mfma_f32_16x16x32_bf16(ka0, qf0, c, 0, 0, 0);
      c = __builtin_amdgcn_mfma_f32_16x16x32_bf16(ka1, qf1, c, 0, 0, 0);
      ps0 += EXP2(c[0]) + EXP2(c[1]);
      ps1 += EXP2(c[2]) + EXP2(c[3]);
    }
    asm volatile("s_waitcnt vmcnt(0)" ::: "memory");
    __builtin_amdgcn_s_barrier();
    cur ^= 1;
  }
  float ps = ps0 + ps1;
  ps += __shfl_xor(ps, 16, 64);  // reduce the 4 k-groups (same q col)
  ps += __shfl_xor(ps, 32, 64);
  float ri = 1.0f / ps;

  // ---- pass 2: QK^T -> P (LDS) -> PV + attn stores ----
  STAGE_K(0, 0);
  STAGE_V(0, 0);
  asm volatile("s_waitcnt vmcnt(0)" ::: "memory");
  __builtin_amdgcn_s_barrier();

  f32x4 cacc[4] = {};
  cur = 0;
#pragma unroll 1
  for (int kt = 0; kt < 32; ++kt) {
    if (kt < 31) {
      STAGE_K(kt + 1, cur ^ 1);
      STAGE_V(kt + 1, cur ^ 1);
    }
    // QK^T (swapped): lane holds P[q=ln15][k=m*16+g*4+r]
#pragma unroll
    for (int m = 0; m < 4; ++m) {
      int r = m * 16 + ln15;
      bf16x8 ka0 = *(const bf16x8*)&sK[cur][r * 64 + ((g ^ (r & 7)) * 8)];
      bf16x8 ka1 = *(const bf16x8*)&sK[cur][r * 64 + (((4 + g) ^ (r & 7)) * 8)];
      f32x4 c = {0.f, 0.f, 0.f, 0.f};
      c = __builtin_amdgcn_mfma_f32_16x16x32_bf16(ka0, qf0, c, 0, 0, 0);
      c = __builtin_amdgcn_mfma_f32_16x16x32_bf16(ka1, qf1, c, 0, 0, 0);
      bf16x4 pb;
      pb[0] = (__bf16)(EXP2(c[0]) * ri);
      pb[1] = (__bf16)(EXP2(c[1]) * ri);
      pb[2] = (__bf16)(EXP2(c[2]) * ri);
      pb[3] = (__bf16)(EXP2(c[3]) * ri);
      *(bf16x4*)&Pl[w * 16 + ln15][m * 16 + g * 4] = pb;
    }
    asm volatile("s_waitcnt lgkmcnt(0)" ::: "memory");  // own P writes visible
    __builtin_amdgcn_sched_barrier(0);                  // rule #18 fence

    // PV: ctx[q][hd] += P[q][k] * V[k][hd]
#pragma unroll
    for (int kk = 0; kk < 2; ++kk) {
      bf16x8 pa = *(const bf16x8*)&Pl[w * 16 + ln15][kk * 32 + g * 8];
#pragma unroll
      for (int n = 0; n < 4; ++n) {
        int vr = n * 16 + ln15;
        bf16x8 vb =
            *(const bf16x8*)&sV[cur][vr * 64 + (((kk * 4 + g) ^ (vr & 7)) * 8)];
        cacc[n] = __builtin_amdgcn_mfma_f32_16x16x32_bf16(pa, vb, cacc[n], 0, 0, 0);
      }
    }

    // attn stores: 16 rows x 256B (cached; L2 coalesces, ~3MB slice/XCD)
    float* ab = attn + ((size_t)(bh * 2048 + q0 + w * 16)) * 2048 + kt * 64 + lane;
#pragma unroll
    for (int r = 0; r < 16; ++r) {
      unsigned short u = (unsigned short)Pl[w * 16 + r][lane];
      ab[(size_t)r * 2048] = b2f(u);
    }

    // drain the 2 staging loads (older), leave the 16 stores in flight
    asm volatile("s_waitcnt vmcnt(16)" ::: "memory");
    __builtin_amdgcn_s_barrier();
    cur ^= 1;
  }

  // ctx epilogue -> (B,S,D) bf16, repacked via own Pl slice to 128B rows
  {
    short* Pw = &Pl[w * 16][0];
#pragma unroll
    for (int n = 0; n < 4; ++n)
#pragma unroll
      for (int r = 0; r < 4; ++r)
        Pw[(g * 4 + r) * 72 + n * 16 + ln15] = (short)f2b(cacc[n][r]);
    asm volatile("s_waitcnt lgkmcnt(0)" ::: "memory");
    __builtin_amdgcn_sched_barrier(0);
    int b = bh >> 4, h = bh & 15;
    int row = lane >> 3, col = (lane & 7) * 8;
#pragma unroll
    for (int i = 0; i < 2; ++i) {
      int q = q0 + w * 16 + i * 8 + row;
      u32x4 pk = *(const u32x4*)&Pw[(i * 8 + row) * 72 + col];
      *(u32x4*)&ws[CTX_OFF + ((size_t)(b * 2048 + q)) * 1024 + h * 64 + col] = pk;
    }
  }
#undef STAGE_K
#undef STAGE_V
}

extern "C" void kernel_launch(void* const* d_in, const int* in_sizes, int n_in,
                              void* d_out, int out_size, void* d_ws, size_t ws_size,
                              hipStream_t stream) {
  const float* q  = (const float*)d_in[0];
  const float* k  = (const float*)d_in[1];
  const float* v  = (const float*)d_in[2];
  const float* wq = (const float*)d_in[3];
  const float* bq = (const float*)d_in[4];
  const float* wk = (const float*)d_in[5];
  const float* bk = (const float*)d_in[6];
  const float* wv = (const float*)d_in[7];
  const float* bv = (const float*)d_in[8];
  const float* wo = (const float*)d_in[9];
  const float* bo = (const float*)d_in[10];
  float* out  = (float*)d_out;
  float* attn = out + 4194304;  // out (2,2048,1024) then attn (2,16,2048,2048)
  short* ws = (short*)d_ws;
  if (ws_size < WS_BYTES) return;  // need 64 MB scratch

  cvt_qkv<<<dim3(4096, 3), 256, 0, stream>>>(q, k, v, ws);
  cvt_wt<<<dim3(32, 32, 4), dim3(32, 8), 0, stream>>>(wq, wk, wv, wo, ws);
  gemm_bf16<<<dim3(8, 32, 3), 256, 0, stream>>>(ws, bq, bk, bv, bo, out, 0);
  attn_k<<<dim3(512), 512, 0, stream>>>(ws, attn);
  gemm_bf16<<<dim3(8, 32, 1), 256, 0, stream>>>(ws, bq, bk, bv, bo, out, 3);
}